// Round 11
// baseline (325.943 us; speedup 1.0000x reference)
//
#include <hip/hip_runtime.h>
#include <hip/hip_fp16.h>

#define NN 100000
#define NE 1600000
#define F 64
#define NG 64
#define BN_EPS 1e-5f
#define EPB 8192
#define NT ((NE + EPB - 1) / EPB)          // 196 edge-tiles
#define NPB 128                             // nodes per bucket (dst>>7)
#define NBKT ((NN + NPB - 1) / NPB)         // 782 buckets
#define CAP 3072                            // max edges per bucket (mean 2048, +22 sigma)
#define NLB ((NN + 63) / 64)                // 1563 linear blocks
#define RED_B 16
#define RPB ((NLB + RED_B - 1) / RED_B)

typedef _Float16 half8 __attribute__((ext_vector_type(8)));
typedef float f32x4 __attribute__((ext_vector_type(4)));

__device__ __forceinline__ float fatomic_add(float* p, float v) {
    return unsafeAtomicAdd(p, v);
}

// kA1: fused init + per-tile LDS bucket sort.
// Writes packed (src | dlow<<17) ints tile-major (full-line, single-block windows)
// and per-tile exclusive bucket prefixes tpre[t][b].
__global__ __launch_bounds__(256) void kA1(const int* __restrict__ src,
                                           const int* __restrict__ dst,
                                           int* __restrict__ pairs,
                                           int* __restrict__ tpre,
                                           float* __restrict__ pooled,
                                           float* __restrict__ sums,
                                           const float* __restrict__ Wg,
                                           __half* __restrict__ Wh) {
    __shared__ int stage[EPB];              // packed edges (load order)
    __shared__ unsigned short keyv[EPB];    // bucket key per edge
    __shared__ int hist[1024];              // padded to 1024
    __shared__ int curb[1024];
    __shared__ int ps[256];
    int t = blockIdx.x, tid = threadIdx.x;

    // fused init (grid 196*256 = 50176 threads covers all)
    int gi = t * 256 + tid;
    if (gi < NG * F) pooled[gi] = 0.f;
    if (gi < 2 * F) sums[gi] = 0.f;
    if (gi < F * F) Wh[gi] = __float2half(Wg[gi]);

    for (int i = tid; i < 1024; i += 256) hist[i] = 0;
    __syncthreads();

    int base = t * EPB;
    int nE = min(EPB, NE - base);
#pragma unroll
    for (int r = 0; r < EPB / 256; ++r) {
        int i = r * 256 + tid;
        if (i < nE) {
            int d = dst[base + i], s = src[base + i];
            int key = d >> 7;
            keyv[i] = (unsigned short)key;
            stage[i] = s | ((d & 127) << 17);
            atomicAdd(&hist[key], 1);
        }
    }
    __syncthreads();
    // exclusive scan of hist[0..1023]: 4 elems/thread + 256-scan
    int h0 = hist[4 * tid], h1 = hist[4 * tid + 1], h2 = hist[4 * tid + 2], h3 = hist[4 * tid + 3];
    int lsum = h0 + h1 + h2 + h3;
    ps[tid] = lsum;
    __syncthreads();
    for (int o = 1; o < 256; o <<= 1) {
        int u = (tid >= o) ? ps[tid - o] : 0;
        __syncthreads();
        ps[tid] += u;
        __syncthreads();
    }
    int ex = ps[tid] - lsum;
    int p0 = ex, p1 = ex + h0, p2 = p1 + h1, p3 = p2 + h2;
    {
        int bb = 4 * tid;
        if (bb < NBKT)     { tpre[t * NBKT + bb]     = p0; curb[bb]     = p0; }
        if (bb + 1 < NBKT) { tpre[t * NBKT + bb + 1] = p1; curb[bb + 1] = p1; }
        if (bb + 2 < NBKT) { tpre[t * NBKT + bb + 2] = p2; curb[bb + 2] = p2; }
        if (bb + 3 < NBKT) { tpre[t * NBKT + bb + 3] = p3; curb[bb + 3] = p3; }
    }
    __syncthreads();
    // scatter within the tile's own 32 KB window
#pragma unroll
    for (int r = 0; r < EPB / 256; ++r) {
        int i = r * 256 + tid;
        if (i < nE) {
            int pos = atomicAdd(&curb[keyv[i]], 1);
            pairs[base + pos] = stage[i];
        }
    }
}

// kSB: bucket totals + exclusive scan -> bstart[NBKT+1]
__global__ __launch_bounds__(1024) void kSB(const int* __restrict__ tpre,
                                            int* __restrict__ bstart) {
    __shared__ int tot[1024];
    int tid = threadIdx.x;
    int acc = 0;
    for (int t = 0; t < NT; ++t) {
        if (tid < NBKT) {
            int a = tpre[t * NBKT + tid];
            int bnd = (tid == NBKT - 1) ? min(EPB, NE - t * EPB) : tpre[t * NBKT + tid + 1];
            acc += bnd - a;
        }
    }
    tot[tid] = (tid < NBKT) ? acc : 0;
    __syncthreads();
    for (int o = 1; o < 1024; o <<= 1) {
        int u = (tid >= o) ? tot[tid - o] : 0;
        __syncthreads();
        tot[tid] += u;
        __syncthreads();
    }
    if (tid < NBKT) bstart[tid] = tot[tid] - acc;   // exclusive
    if (tid == NBKT - 1) bstart[NBKT] = tot[tid];   // == NE
}

// kB2: per-bucket: gather 196 runs -> LDS counting sort -> csrc stream + offs/dinv/dn2
__global__ __launch_bounds__(256) void kB2(const int* __restrict__ pairs,
                                           const int* __restrict__ tpre,
                                           const int* __restrict__ bstart,
                                           int* __restrict__ csrc,
                                           int* __restrict__ offs,
                                           float* __restrict__ dinv,
                                           float* __restrict__ dn2) {
    __shared__ int lsrc[CAP];
    __shared__ unsigned char ldl[CAP];
    __shared__ int lo[CAP];
    __shared__ int toff[NT], rstart[NT];
    __shared__ int sc[256];
    __shared__ int hist[NPB], pre2[NPB], curl[NPB];
    int b = blockIdx.x, tid = threadIdx.x;
    int s0 = bstart[b];

    int len = 0;
    if (tid < NT) {
        int a = tpre[tid * NBKT + b];
        int bnd = (b == NBKT - 1) ? min(EPB, NE - tid * EPB) : tpre[tid * NBKT + b + 1];
        rstart[tid] = a;
        len = bnd - a;
    }
    sc[tid] = len;
    __syncthreads();
    for (int o = 1; o < 256; o <<= 1) {
        int u = (tid >= o) ? sc[tid - o] : 0;
        __syncthreads();
        sc[tid] += u;
        __syncthreads();
    }
    if (tid < NT) toff[tid] = sc[tid] - len;   // exclusive
    int cnt = min(sc[255], CAP);
    __syncthreads();
    // copy runs into LDS (pairs are L2-resident)
    if (tid < NT) {
        int o2 = toff[tid];
        const int* p = pairs + tid * EPB + rstart[tid];
        for (int k = 0; k < len && o2 + k < CAP; ++k) {
            int pk = p[k];
            lsrc[o2 + k] = pk & 0x1FFFF;
            ldl[o2 + k] = (unsigned char)(pk >> 17);
        }
    }
    if (tid < NPB) hist[tid] = 0;
    __syncthreads();
    for (int i = tid; i < cnt; i += 256) atomicAdd(&hist[ldl[i]], 1);
    __syncthreads();
    int dg = (tid < NPB) ? hist[tid] : 0;
    if (tid < NPB) pre2[tid] = dg;
    __syncthreads();
    for (int o = 1; o < NPB; o <<= 1) {
        int u = (tid < NPB && tid >= o) ? pre2[tid - o] : 0;
        __syncthreads();
        if (tid < NPB) pre2[tid] += u;
        __syncthreads();
    }
    if (tid < NPB) {
        int exn = pre2[tid] - dg;
        curl[tid] = exn;
        int n = b * NPB + tid;
        if (n < NN) {
            offs[n] = s0 + exn;
            float r = rsqrtf((float)(dg + 1));   // deg = in-edges + self loop
            dinv[n] = r;
            dn2[n] = r * r;
        }
    }
    if (b == 0 && tid == 0) offs[NN] = NE;
    __syncthreads();
    for (int i = tid; i < cnt; i += 256) {
        int pos = atomicAdd(&curl[ldl[i]], 1);   // LDS atomic only
        lo[pos] = lsrc[i];
    }
    __syncthreads();
    for (int i = tid; i < cnt; i += 256) csrc[s0 + i] = lo[i];   // full-line stream
}

// u0 = dinv (.) x   (fp32 -> fp16, 2 elems/thread)
__global__ void k_u0(const float2* __restrict__ x2, const float* __restrict__ dinv,
                     __half2* __restrict__ u2) {
    int i = blockIdx.x * blockDim.x + threadIdx.x;   // NN*F/2
    if (i >= NN * F / 2) return;
    float2 v = x2[i];
    float d = dinv[i >> 5];
    u2[i] = __floats2half2_rn(v.x * d, v.y * d);
}

// u_out[n,:] = oscale[n] * (u_in[n,:] + sum_{s in Nin(n)} u_in[s,:])
// wave = 2 nodes: lanes 0-31 -> node 2w, lanes 32-63 -> node 2w+1
__global__ __launch_bounds__(256) void k_hop(const int* __restrict__ offs,
                                             const int* __restrict__ csrc,
                                             const float* __restrict__ oscale,
                                             const __half2* __restrict__ uin,
                                             __half2* __restrict__ uout) {
    int wv = blockIdx.x * 4 + (threadIdx.x >> 6);
    int lane = threadIdx.x & 63;
    int n = wv * 2 + (lane >> 5);      // NN = 12500*4*2 exactly
    int c = lane & 31;
    float2 acc = __half22float2(uin[n * 32 + c]);
    int e = offs[n], end = offs[n + 1];
    for (; e + 8 <= end; e += 8) {
        int s0 = csrc[e],     s1 = csrc[e + 1], s2 = csrc[e + 2], s3 = csrc[e + 3];
        int s4 = csrc[e + 4], s5 = csrc[e + 5], s6 = csrc[e + 6], s7 = csrc[e + 7];
        float2 f0 = __half22float2(uin[s0 * 32 + c]);
        float2 f1 = __half22float2(uin[s1 * 32 + c]);
        float2 f2 = __half22float2(uin[s2 * 32 + c]);
        float2 f3 = __half22float2(uin[s3 * 32 + c]);
        float2 f4 = __half22float2(uin[s4 * 32 + c]);
        float2 f5 = __half22float2(uin[s5 * 32 + c]);
        float2 f6 = __half22float2(uin[s6 * 32 + c]);
        float2 f7 = __half22float2(uin[s7 * 32 + c]);
        acc.x += ((f0.x + f1.x) + (f2.x + f3.x)) + ((f4.x + f5.x) + (f6.x + f7.x));
        acc.y += ((f0.y + f1.y) + (f2.y + f3.y)) + ((f4.y + f5.y) + (f6.y + f7.y));
    }
    for (; e < end; ++e) {
        float2 f = __half22float2(uin[csrc[e] * 32 + c]);
        acc.x += f.x; acc.y += f.y;
    }
    float os = oscale[n];
    uout[n * 32 + c] = __floats2half2_rn(acc.x * os, acc.y * os);
}

// y = relu(h @ Wh^T + b) via MFMA; per-block partial stats -> psum (no atomics)
__global__ __launch_bounds__(256) void k_linear(const __half* __restrict__ h,
                                                const __half* __restrict__ Wh,
                                                const float* __restrict__ bg,
                                                __half* __restrict__ y,
                                                float* __restrict__ psum) {
    __shared__ float sred[4][64], qred[4][64];
    int tid = threadIdx.x;
    int wid = tid >> 6, lane = tid & 63;
    int lo = lane & 15, hi = lane >> 4;
    int n0 = blockIdx.x * 64 + wid * 16;

    half8 bf[4][2];
#pragma unroll
    for (int ct = 0; ct < 4; ++ct)
#pragma unroll
        for (int kk = 0; kk < 2; ++kk)
            bf[ct][kk] = *(const half8*)(Wh + (ct * 16 + lo) * 64 + kk * 32 + hi * 8);

    int arow = n0 + lo;
    half8 af[2];
    if (arow < NN) {
        af[0] = *(const half8*)(h + arow * 64 + hi * 8);
        af[1] = *(const half8*)(h + arow * 64 + 32 + hi * 8);
    } else {
#pragma unroll
        for (int j = 0; j < 8; ++j) { af[0][j] = (_Float16)0; af[1][j] = (_Float16)0; }
    }

    f32x4 acc[4];
#pragma unroll
    for (int ct = 0; ct < 4; ++ct) {
        acc[ct] = (f32x4){0.f, 0.f, 0.f, 0.f};
        acc[ct] = __builtin_amdgcn_mfma_f32_16x16x32_f16(af[0], bf[ct][0], acc[ct], 0, 0, 0);
        acc[ct] = __builtin_amdgcn_mfma_f32_16x16x32_f16(af[1], bf[ct][1], acc[ct], 0, 0, 0);
    }

#pragma unroll
    for (int ct = 0; ct < 4; ++ct) {
        int j = ct * 16 + lo;
        float bj = bg[j];
        float ls = 0.f, lq = 0.f;
#pragma unroll
        for (int r = 0; r < 4; ++r) {
            int n = n0 + hi * 4 + r;
            if (n < NN) {
                float v = fmaxf(acc[ct][r] + bj, 0.f);
                y[n * 64 + j] = __float2half(v);
                ls += v; lq += v * v;
            }
        }
        ls += __shfl_xor(ls, 16, 64); ls += __shfl_xor(ls, 32, 64);
        lq += __shfl_xor(lq, 16, 64); lq += __shfl_xor(lq, 32, 64);
        if (hi == 0) { sred[wid][j] = ls; qred[wid][j] = lq; }
    }
    __syncthreads();
    if (tid < 128) {
        int c = tid & 63;
        float v = (tid < 64)
            ? (sred[0][c] + sred[1][c] + sred[2][c] + sred[3][c])
            : (qred[0][c] + qred[1][c] + qred[2][c] + qred[3][c]);
        psum[blockIdx.x * 128 + tid] = v;
    }
}

// reduce psum[NLB][128] -> sums[128]
__global__ __launch_bounds__(256) void k_red(const float* __restrict__ psum,
                                             float* __restrict__ sums) {
    int t = threadIdx.x;
    int c = t & 127, half = t >> 7;
    int r0 = blockIdx.x * RPB + half;
    int r1 = min((int)(blockIdx.x + 1) * RPB, NLB);
    float s = 0.f;
    for (int r = r0; r < r1; r += 2)
        s += psum[r * 128 + c];
    __shared__ float sh[128];
    if (half == 0) sh[c] = s;
    __syncthreads();
    if (half == 1) fatomic_add(&sums[c], s + sh[c]);
}

// BN affine + normalize + pooled segment-sum
__global__ __launch_bounds__(256) void k_normpool(const __half* __restrict__ y,
                                                  const int* __restrict__ batch,
                                                  const float* __restrict__ sums,
                                                  const float* __restrict__ gamma,
                                                  const float* __restrict__ beta,
                                                  float* __restrict__ outh,
                                                  float* __restrict__ pooled) {
    int tid = threadIdx.x;
    int j = tid & 63, nl = tid >> 6;
    float mean = sums[j] * (1.0f / NN);
    float var = sums[64 + j] * (1.0f / NN) - mean * mean;
    float rinv = rsqrtf(var + BN_EPS);
    float a = gamma[j] * rinv;
    float c = beta[j] - mean * a;
    int base = blockIdx.x * 256;
    int curg = -1;
    float acc = 0.f;
    for (int it = 0; it < 64; ++it) {
        int n = base + it * 4 + nl;
        if (n >= NN) break;
        int g = batch[n];
        float v = fmaf(__half2float(y[n * 64 + j]), a, c);
        outh[(size_t)n * 64 + j] = v;
        if (g != curg) {
            if (curg >= 0) fatomic_add(&pooled[curg * 64 + j], acc);
            curg = g; acc = 0.f;
        }
        acc += v;
    }
    if (curg >= 0) fatomic_add(&pooled[curg * 64 + j], acc);
}

extern "C" void kernel_launch(void* const* d_in, const int* in_sizes, int n_in,
                              void* d_out, int out_size, void* d_ws, size_t ws_size,
                              hipStream_t stream) {
    const float* x     = (const float*)d_in[0];
    const int*   ei    = (const int*)d_in[1];
    const int*   batch = (const int*)d_in[2];
    const float* W     = (const float*)d_in[3];
    const float* b     = (const float*)d_in[4];
    const float* gamma = (const float*)d_in[5];
    const float* beta  = (const float*)d_in[6];
    const int* src = ei;
    const int* dst = ei + NE;

    float* pooled = (float*)d_out;
    float* outh   = (float*)d_out + NG * F;

    char* w = (char*)d_ws;
    float* dinv   = (float*)w;  w += sizeof(float) * NN;
    float* dn2    = (float*)w;  w += sizeof(float) * NN;
    int*   offs   = (int*)w;    w += sizeof(int) * (NN + 1);
    float* sums   = (float*)w;  w += sizeof(float) * 2 * F;
    __half* Wh    = (__half*)w; w += sizeof(__half) * F * F;
    float* psum   = (float*)w;  w += sizeof(float) * NLB * 128;
    int*   tpre   = (int*)w;    w += sizeof(int) * NT * NBKT;
    int*   bstart = (int*)w;    w += sizeof(int) * (NBKT + 1);
    int*   csrc   = (int*)w;    w += sizeof(int) * NE;
    // union region (25.6 MB): pairs (6.4 MB, live kA1..kB2) -> ubufA (u0 onward)
    char* uni = w;
    __half* ubufA = (__half*)uni;
    __half* ubufB = (__half*)(uni + sizeof(__half) * NN * F);
    int*    pairs = (int*)uni;

    const int B = 256;
    dim3 blk(B);

    kA1<<<dim3(NT), blk, 0, stream>>>(src, dst, pairs, tpre, pooled, sums, W, Wh);
    kSB<<<dim3(1), dim3(1024), 0, stream>>>(tpre, bstart);
    kB2<<<dim3(NBKT), blk, 0, stream>>>(pairs, tpre, bstart, csrc, offs, dinv, dn2);

    // u0 = dinv.x -> ubufA  (pairs dead from here on)
    k_u0<<<dim3((NN * F / 2 + B - 1) / B), blk, 0, stream>>>((const float2*)x, dinv, (__half2*)ubufA);

    dim3 gh(NN / 8);   // 12500 blocks, 4 waves/block, 2 nodes/wave
    k_hop<<<gh, blk, 0, stream>>>(offs, csrc, dn2,  (const __half2*)ubufA, (__half2*)ubufB);
    k_hop<<<gh, blk, 0, stream>>>(offs, csrc, dn2,  (const __half2*)ubufB, (__half2*)ubufA);
    k_hop<<<gh, blk, 0, stream>>>(offs, csrc, dinv, (const __half2*)ubufA, (__half2*)ubufB);

    // linear + relu (MFMA), contention-free stats: ubufB(h) -> y in ubufA
    __half* yh = ubufA;
    k_linear<<<dim3(NLB), blk, 0, stream>>>(ubufB, Wh, b, yh, psum);
    k_red<<<dim3(RED_B), blk, 0, stream>>>(psum, sums);
    k_normpool<<<dim3((NN + 255) / 256), blk, 0, stream>>>(yh, batch, sums, gamma, beta, outh, pooled);
}

// Round 12
// 293.511 us; speedup vs baseline: 1.1105x; 1.1105x over previous
//
#include <hip/hip_runtime.h>
#include <hip/hip_fp16.h>

#define NN 100000
#define NE 1600000
#define F 64
#define NG 64
#define BN_EPS 1e-5f
#define EPB 8192
#define NT ((NE + EPB - 1) / EPB)          // 196 edge-tiles
#define NPB 128                             // nodes per bucket (dst>>7)
#define NBKT ((NN + NPB - 1) / NPB)         // 782 buckets
#define CAP 3072                            // max edges per bucket (mean 2048, +22 sigma)
#define NLB ((NN + 63) / 64)                // 1563 linear blocks
#define RED_B 16
#define RPB ((NLB + RED_B - 1) / RED_B)

typedef _Float16 half8 __attribute__((ext_vector_type(8)));
typedef float f32x4 __attribute__((ext_vector_type(4)));

__device__ __forceinline__ float fatomic_add(float* p, float v) {
    return unsafeAtomicAdd(p, v);
}

// kA1: fused init + per-tile LDS bucket sort + bucket-total atomics.
// Writes packed (src | dlow<<17) ints tile-major (full-line, single-block windows),
// per-tile exclusive bucket prefixes tpre[t][b], and btot[b] += per-tile count.
__global__ __launch_bounds__(256) void kA1(const int* __restrict__ src,
                                           const int* __restrict__ dst,
                                           int* __restrict__ pairs,
                                           int* __restrict__ tpre,
                                           int* __restrict__ btot,
                                           float* __restrict__ pooled,
                                           float* __restrict__ sums,
                                           const float* __restrict__ Wg,
                                           __half* __restrict__ Wh) {
    __shared__ int stage[EPB];              // packed edges (load order)
    __shared__ unsigned short keyv[EPB];    // bucket key per edge
    __shared__ int hist[1024];              // padded to 1024
    __shared__ int curb[1024];
    __shared__ int ps[256];
    int t = blockIdx.x, tid = threadIdx.x;

    // fused init (grid 196*256 = 50176 threads covers all)
    int gi = t * 256 + tid;
    if (gi < NG * F) pooled[gi] = 0.f;
    if (gi < 2 * F) sums[gi] = 0.f;
    if (gi < F * F) Wh[gi] = __float2half(Wg[gi]);

    for (int i = tid; i < 1024; i += 256) hist[i] = 0;
    __syncthreads();

    int base = t * EPB;
    int nE = min(EPB, NE - base);
#pragma unroll
    for (int r = 0; r < EPB / 256; ++r) {
        int i = r * 256 + tid;
        if (i < nE) {
            int d = dst[base + i], s = src[base + i];
            int key = d >> 7;
            keyv[i] = (unsigned short)key;
            stage[i] = s | ((d & 127) << 17);
            atomicAdd(&hist[key], 1);
        }
    }
    __syncthreads();
    // exclusive scan of hist[0..1023]: 4 elems/thread + 256-scan
    int h0 = hist[4 * tid], h1 = hist[4 * tid + 1], h2 = hist[4 * tid + 2], h3 = hist[4 * tid + 3];
    int lsum = h0 + h1 + h2 + h3;
    ps[tid] = lsum;
    __syncthreads();
    for (int o = 1; o < 256; o <<= 1) {
        int u = (tid >= o) ? ps[tid - o] : 0;
        __syncthreads();
        ps[tid] += u;
        __syncthreads();
    }
    int ex = ps[tid] - lsum;
    int p0 = ex, p1 = ex + h0, p2 = p1 + h1, p3 = p2 + h2;
    {
        int bb = 4 * tid;
        if (bb < NBKT)     { tpre[t * NBKT + bb]     = p0; curb[bb]     = p0; if (h0) atomicAdd(&btot[bb],     h0); }
        if (bb + 1 < NBKT) { tpre[t * NBKT + bb + 1] = p1; curb[bb + 1] = p1; if (h1) atomicAdd(&btot[bb + 1], h1); }
        if (bb + 2 < NBKT) { tpre[t * NBKT + bb + 2] = p2; curb[bb + 2] = p2; if (h2) atomicAdd(&btot[bb + 2], h2); }
        if (bb + 3 < NBKT) { tpre[t * NBKT + bb + 3] = p3; curb[bb + 3] = p3; if (h3) atomicAdd(&btot[bb + 3], h3); }
    }
    __syncthreads();
    // scatter within the tile's own 32 KB window
#pragma unroll
    for (int r = 0; r < EPB / 256; ++r) {
        int i = r * 256 + tid;
        if (i < nE) {
            int pos = atomicAdd(&curb[keyv[i]], 1);
            pairs[base + pos] = stage[i];
        }
    }
}

// kSB: single-pass exclusive scan of btot[NBKT] -> bstart[NBKT+1]
__global__ __launch_bounds__(1024) void kSB(const int* __restrict__ btot,
                                            int* __restrict__ bstart) {
    __shared__ int tot[1024];
    int tid = threadIdx.x;
    int v = (tid < NBKT) ? btot[tid] : 0;
    tot[tid] = v;
    __syncthreads();
    for (int o = 1; o < 1024; o <<= 1) {
        int u = (tid >= o) ? tot[tid - o] : 0;
        __syncthreads();
        tot[tid] += u;
        __syncthreads();
    }
    if (tid < NBKT) bstart[tid] = tot[tid] - v;     // exclusive
    if (tid == NBKT - 1) bstart[NBKT] = tot[tid];   // == NE
}

// kB2: per-bucket: gather 196 runs -> LDS counting sort -> csrc stream + offs/dinv/dn2
__global__ __launch_bounds__(256) void kB2(const int* __restrict__ pairs,
                                           const int* __restrict__ tpre,
                                           const int* __restrict__ bstart,
                                           int* __restrict__ csrc,
                                           int* __restrict__ offs,
                                           float* __restrict__ dinv,
                                           float* __restrict__ dn2) {
    __shared__ int lsrc[CAP];
    __shared__ unsigned char ldl[CAP];
    __shared__ int lo[CAP];
    __shared__ int toff[NT], rstart[NT];
    __shared__ int sc[256];
    __shared__ int hist[NPB], pre2[NPB], curl[NPB];
    int b = blockIdx.x, tid = threadIdx.x;
    int s0 = bstart[b];

    int len = 0;
    if (tid < NT) {
        int a = tpre[tid * NBKT + b];
        int bnd = (b == NBKT - 1) ? min(EPB, NE - tid * EPB) : tpre[tid * NBKT + b + 1];
        rstart[tid] = a;
        len = bnd - a;
    }
    sc[tid] = len;
    __syncthreads();
    for (int o = 1; o < 256; o <<= 1) {
        int u = (tid >= o) ? sc[tid - o] : 0;
        __syncthreads();
        sc[tid] += u;
        __syncthreads();
    }
    if (tid < NT) toff[tid] = sc[tid] - len;   // exclusive
    int cnt = min(sc[255], CAP);
    __syncthreads();
    // copy runs into LDS (pairs are L2-resident)
    if (tid < NT) {
        int o2 = toff[tid];
        const int* p = pairs + tid * EPB + rstart[tid];
        for (int k = 0; k < len && o2 + k < CAP; ++k) {
            int pk = p[k];
            lsrc[o2 + k] = pk & 0x1FFFF;
            ldl[o2 + k] = (unsigned char)(pk >> 17);
        }
    }
    if (tid < NPB) hist[tid] = 0;
    __syncthreads();
    for (int i = tid; i < cnt; i += 256) atomicAdd(&hist[ldl[i]], 1);
    __syncthreads();
    int dg = (tid < NPB) ? hist[tid] : 0;
    if (tid < NPB) pre2[tid] = dg;
    __syncthreads();
    for (int o = 1; o < NPB; o <<= 1) {
        int u = (tid < NPB && tid >= o) ? pre2[tid - o] : 0;
        __syncthreads();
        if (tid < NPB) pre2[tid] += u;
        __syncthreads();
    }
    if (tid < NPB) {
        int exn = pre2[tid] - dg;
        curl[tid] = exn;
        int n = b * NPB + tid;
        if (n < NN) {
            offs[n] = s0 + exn;
            float r = rsqrtf((float)(dg + 1));   // deg = in-edges + self loop
            dinv[n] = r;
            dn2[n] = r * r;
        }
    }
    if (b == 0 && tid == 0) offs[NN] = NE;
    __syncthreads();
    for (int i = tid; i < cnt; i += 256) {
        int pos = atomicAdd(&curl[ldl[i]], 1);   // LDS atomic only
        lo[pos] = lsrc[i];
    }
    __syncthreads();
    for (int i = tid; i < cnt; i += 256) csrc[s0 + i] = lo[i];   // full-line stream
}

// u0 = dinv (.) x   (fp32 -> fp16, 2 elems/thread)
__global__ void k_u0(const float2* __restrict__ x2, const float* __restrict__ dinv,
                     __half2* __restrict__ u2) {
    int i = blockIdx.x * blockDim.x + threadIdx.x;   // NN*F/2
    if (i >= NN * F / 2) return;
    float2 v = x2[i];
    float d = dinv[i >> 5];
    u2[i] = __floats2half2_rn(v.x * d, v.y * d);
}

// u_out[n,:] = oscale[n] * (u_in[n,:] + sum_{s in Nin(n)} u_in[s,:])
// wave = 2 nodes: lanes 0-31 -> node 2w, lanes 32-63 -> node 2w+1
__global__ __launch_bounds__(256) void k_hop(const int* __restrict__ offs,
                                             const int* __restrict__ csrc,
                                             const float* __restrict__ oscale,
                                             const __half2* __restrict__ uin,
                                             __half2* __restrict__ uout) {
    int wv = blockIdx.x * 4 + (threadIdx.x >> 6);
    int lane = threadIdx.x & 63;
    int n = wv * 2 + (lane >> 5);      // NN = 12500*4*2 exactly
    int c = lane & 31;
    float2 acc = __half22float2(uin[n * 32 + c]);
    int e = offs[n], end = offs[n + 1];
    for (; e + 8 <= end; e += 8) {
        int s0 = csrc[e],     s1 = csrc[e + 1], s2 = csrc[e + 2], s3 = csrc[e + 3];
        int s4 = csrc[e + 4], s5 = csrc[e + 5], s6 = csrc[e + 6], s7 = csrc[e + 7];
        float2 f0 = __half22float2(uin[s0 * 32 + c]);
        float2 f1 = __half22float2(uin[s1 * 32 + c]);
        float2 f2 = __half22float2(uin[s2 * 32 + c]);
        float2 f3 = __half22float2(uin[s3 * 32 + c]);
        float2 f4 = __half22float2(uin[s4 * 32 + c]);
        float2 f5 = __half22float2(uin[s5 * 32 + c]);
        float2 f6 = __half22float2(uin[s6 * 32 + c]);
        float2 f7 = __half22float2(uin[s7 * 32 + c]);
        acc.x += ((f0.x + f1.x) + (f2.x + f3.x)) + ((f4.x + f5.x) + (f6.x + f7.x));
        acc.y += ((f0.y + f1.y) + (f2.y + f3.y)) + ((f4.y + f5.y) + (f6.y + f7.y));
    }
    for (; e < end; ++e) {
        float2 f = __half22float2(uin[csrc[e] * 32 + c]);
        acc.x += f.x; acc.y += f.y;
    }
    float os = oscale[n];
    uout[n * 32 + c] = __floats2half2_rn(acc.x * os, acc.y * os);
}

// y = relu(h @ Wh^T + b) via MFMA; per-block partial stats -> psum (no atomics)
__global__ __launch_bounds__(256) void k_linear(const __half* __restrict__ h,
                                                const __half* __restrict__ Wh,
                                                const float* __restrict__ bg,
                                                __half* __restrict__ y,
                                                float* __restrict__ psum) {
    __shared__ float sred[4][64], qred[4][64];
    int tid = threadIdx.x;
    int wid = tid >> 6, lane = tid & 63;
    int lo = lane & 15, hi = lane >> 4;
    int n0 = blockIdx.x * 64 + wid * 16;

    half8 bf[4][2];
#pragma unroll
    for (int ct = 0; ct < 4; ++ct)
#pragma unroll
        for (int kk = 0; kk < 2; ++kk)
            bf[ct][kk] = *(const half8*)(Wh + (ct * 16 + lo) * 64 + kk * 32 + hi * 8);

    int arow = n0 + lo;
    half8 af[2];
    if (arow < NN) {
        af[0] = *(const half8*)(h + arow * 64 + hi * 8);
        af[1] = *(const half8*)(h + arow * 64 + 32 + hi * 8);
    } else {
#pragma unroll
        for (int j = 0; j < 8; ++j) { af[0][j] = (_Float16)0; af[1][j] = (_Float16)0; }
    }

    f32x4 acc[4];
#pragma unroll
    for (int ct = 0; ct < 4; ++ct) {
        acc[ct] = (f32x4){0.f, 0.f, 0.f, 0.f};
        acc[ct] = __builtin_amdgcn_mfma_f32_16x16x32_f16(af[0], bf[ct][0], acc[ct], 0, 0, 0);
        acc[ct] = __builtin_amdgcn_mfma_f32_16x16x32_f16(af[1], bf[ct][1], acc[ct], 0, 0, 0);
    }

#pragma unroll
    for (int ct = 0; ct < 4; ++ct) {
        int j = ct * 16 + lo;
        float bj = bg[j];
        float ls = 0.f, lq = 0.f;
#pragma unroll
        for (int r = 0; r < 4; ++r) {
            int n = n0 + hi * 4 + r;
            if (n < NN) {
                float v = fmaxf(acc[ct][r] + bj, 0.f);
                y[n * 64 + j] = __float2half(v);
                ls += v; lq += v * v;
            }
        }
        ls += __shfl_xor(ls, 16, 64); ls += __shfl_xor(ls, 32, 64);
        lq += __shfl_xor(lq, 16, 64); lq += __shfl_xor(lq, 32, 64);
        if (hi == 0) { sred[wid][j] = ls; qred[wid][j] = lq; }
    }
    __syncthreads();
    if (tid < 128) {
        int c = tid & 63;
        float v = (tid < 64)
            ? (sred[0][c] + sred[1][c] + sred[2][c] + sred[3][c])
            : (qred[0][c] + qred[1][c] + qred[2][c] + qred[3][c]);
        psum[blockIdx.x * 128 + tid] = v;
    }
}

// reduce psum[NLB][128] -> sums[128]
__global__ __launch_bounds__(256) void k_red(const float* __restrict__ psum,
                                             float* __restrict__ sums) {
    int t = threadIdx.x;
    int c = t & 127, half = t >> 7;
    int r0 = blockIdx.x * RPB + half;
    int r1 = min((int)(blockIdx.x + 1) * RPB, NLB);
    float s = 0.f;
    for (int r = r0; r < r1; r += 2)
        s += psum[r * 128 + c];
    __shared__ float sh[128];
    if (half == 0) sh[c] = s;
    __syncthreads();
    if (half == 1) fatomic_add(&sums[c], s + sh[c]);
}

// BN affine + normalize + pooled segment-sum
__global__ __launch_bounds__(256) void k_normpool(const __half* __restrict__ y,
                                                  const int* __restrict__ batch,
                                                  const float* __restrict__ sums,
                                                  const float* __restrict__ gamma,
                                                  const float* __restrict__ beta,
                                                  float* __restrict__ outh,
                                                  float* __restrict__ pooled) {
    int tid = threadIdx.x;
    int j = tid & 63, nl = tid >> 6;
    float mean = sums[j] * (1.0f / NN);
    float var = sums[64 + j] * (1.0f / NN) - mean * mean;
    float rinv = rsqrtf(var + BN_EPS);
    float a = gamma[j] * rinv;
    float c = beta[j] - mean * a;
    int base = blockIdx.x * 256;
    int curg = -1;
    float acc = 0.f;
    for (int it = 0; it < 64; ++it) {
        int n = base + it * 4 + nl;
        if (n >= NN) break;
        int g = batch[n];
        float v = fmaf(__half2float(y[n * 64 + j]), a, c);
        outh[(size_t)n * 64 + j] = v;
        if (g != curg) {
            if (curg >= 0) fatomic_add(&pooled[curg * 64 + j], acc);
            curg = g; acc = 0.f;
        }
        acc += v;
    }
    if (curg >= 0) fatomic_add(&pooled[curg * 64 + j], acc);
}

extern "C" void kernel_launch(void* const* d_in, const int* in_sizes, int n_in,
                              void* d_out, int out_size, void* d_ws, size_t ws_size,
                              hipStream_t stream) {
    const float* x     = (const float*)d_in[0];
    const int*   ei    = (const int*)d_in[1];
    const int*   batch = (const int*)d_in[2];
    const float* W     = (const float*)d_in[3];
    const float* b     = (const float*)d_in[4];
    const float* gamma = (const float*)d_in[5];
    const float* beta  = (const float*)d_in[6];
    const int* src = ei;
    const int* dst = ei + NE;

    float* pooled = (float*)d_out;
    float* outh   = (float*)d_out + NG * F;

    char* w = (char*)d_ws;
    float* dinv   = (float*)w;  w += sizeof(float) * NN;
    float* dn2    = (float*)w;  w += sizeof(float) * NN;
    int*   offs   = (int*)w;    w += sizeof(int) * (NN + 1);
    float* sums   = (float*)w;  w += sizeof(float) * 2 * F;
    __half* Wh    = (__half*)w; w += sizeof(__half) * F * F;
    float* psum   = (float*)w;  w += sizeof(float) * NLB * 128;
    int*   tpre   = (int*)w;    w += sizeof(int) * NT * NBKT;
    int*   btot   = (int*)w;    w += sizeof(int) * NBKT;
    int*   bstart = (int*)w;    w += sizeof(int) * (NBKT + 1);
    int*   csrc   = (int*)w;    w += sizeof(int) * NE;
    // union region (25.6 MB): pairs (6.4 MB, live kA1..kB2) -> ubufA (u0 onward)
    char* uni = w;
    __half* ubufA = (__half*)uni;
    __half* ubufB = (__half*)(uni + sizeof(__half) * NN * F);
    int*    pairs = (int*)uni;

    const int B = 256;
    dim3 blk(B);

    hipMemsetAsync(btot, 0, sizeof(int) * NBKT, stream);
    kA1<<<dim3(NT), blk, 0, stream>>>(src, dst, pairs, tpre, btot, pooled, sums, W, Wh);
    kSB<<<dim3(1), dim3(1024), 0, stream>>>(btot, bstart);
    kB2<<<dim3(NBKT), blk, 0, stream>>>(pairs, tpre, bstart, csrc, offs, dinv, dn2);

    // u0 = dinv.x -> ubufA  (pairs dead from here on)
    k_u0<<<dim3((NN * F / 2 + B - 1) / B), blk, 0, stream>>>((const float2*)x, dinv, (__half2*)ubufA);

    dim3 gh(NN / 8);   // 12500 blocks, 4 waves/block, 2 nodes/wave
    k_hop<<<gh, blk, 0, stream>>>(offs, csrc, dn2,  (const __half2*)ubufA, (__half2*)ubufB);
    k_hop<<<gh, blk, 0, stream>>>(offs, csrc, dn2,  (const __half2*)ubufB, (__half2*)ubufA);
    k_hop<<<gh, blk, 0, stream>>>(offs, csrc, dinv, (const __half2*)ubufA, (__half2*)ubufB);

    // linear + relu (MFMA), contention-free stats: ubufB(h) -> y in ubufA
    __half* yh = ubufA;
    k_linear<<<dim3(NLB), blk, 0, stream>>>(ubufB, Wh, b, yh, psum);
    k_red<<<dim3(RED_B), blk, 0, stream>>>(psum, sums);
    k_normpool<<<dim3((NN + 255) / 256), blk, 0, stream>>>(yh, batch, sums, gamma, beta, outh, pooled);
}

// Round 14
// 273.552 us; speedup vs baseline: 1.1915x; 1.0730x over previous
//
#include <hip/hip_runtime.h>
#include <hip/hip_fp16.h>

#define NN 100000
#define NE 1600000
#define F 64
#define NG 64
#define BN_EPS 1e-5f
#define EPB 8192
#define NT ((NE + EPB - 1) / EPB)          // 196 edge-tiles
#define NPB 128                             // nodes per bucket (dst>>7)
#define NBKT ((NN + NPB - 1) / NPB)         // 782 buckets
#define M_CNT (NBKT * NT)                   // 153272 counters
#define NSB ((M_CNT + 1023) / 1024)         // 150 scan blocks
#define CAP 3072                            // max edges per bucket (mean 2048, +22 sigma)
#define NLB ((NN + 63) / 64)                // 1563 linear blocks
#define RED_B 16
#define RPB ((NLB + RED_B - 1) / RED_B)

typedef _Float16 half8 __attribute__((ext_vector_type(8)));
typedef float f32x4 __attribute__((ext_vector_type(4)));

__device__ __forceinline__ float fatomic_add(float* p, float v) {
    return unsafeAtomicAdd(p, v);
}

// A1: fused init + per-tile histogram over 782 node-buckets
__global__ __launch_bounds__(256) void kA1(const int* __restrict__ dst,
                                           int* __restrict__ cnt,
                                           float* __restrict__ pooled,
                                           float* __restrict__ sums,
                                           const float* __restrict__ Wg,
                                           __half* __restrict__ Wh) {
    __shared__ int hist[NBKT];
    int t = threadIdx.x;
    int gi = blockIdx.x * 256 + t;
    if (gi < NG * F) pooled[gi] = 0.f;
    if (gi < 2 * F) sums[gi] = 0.f;
    if (gi < F * F) Wh[gi] = __float2half(Wg[gi]);
    for (int i = t; i < NBKT; i += 256) hist[i] = 0;
    __syncthreads();
    int base = blockIdx.x * EPB;
#pragma unroll
    for (int r = 0; r < EPB / 256; ++r) {
        int e = base + r * 256 + t;
        if (e < NE) atomicAdd(&hist[dst[e] >> 7], 1);
    }
    __syncthreads();
    for (int i = t; i < NBKT; i += 256)
        cnt[i * NT + blockIdx.x] = hist[i];   // bucket-major layout for the scan
}

// S1: per-1024-chunk partial sums of cnt
__global__ __launch_bounds__(1024) void kS1(const int* __restrict__ cnt,
                                            int* __restrict__ part) {
    int t = threadIdx.x;
    int i = blockIdx.x * 1024 + t;
    int v = (i < M_CNT) ? cnt[i] : 0;
#pragma unroll
    for (int o = 32; o > 0; o >>= 1) v += __shfl_down(v, o, 64);
    __shared__ int ws[16];
    if ((t & 63) == 0) ws[t >> 6] = v;
    __syncthreads();
    if (t == 0) {
        int s = 0;
#pragma unroll
        for (int k = 0; k < 16; ++k) s += ws[k];
        part[blockIdx.x] = s;
    }
}

// S2: exclusive scan of the 150 partials (in place)
__global__ __launch_bounds__(256) void kS2(int* __restrict__ part) {
    __shared__ int sh[256];
    int t = threadIdx.x;
    int v = (t < NSB) ? part[t] : 0;
    sh[t] = v;
    __syncthreads();
    for (int o = 1; o < 256; o <<= 1) {
        int u = (t >= o) ? sh[t - o] : 0;
        __syncthreads();
        sh[t] += u;
        __syncthreads();
    }
    if (t < NSB) part[t] = sh[t] - v;
}

// S3: local scan + partial offset -> cscan (global exclusive scan of cnt)
__global__ __launch_bounds__(1024) void kS3(const int* __restrict__ cnt,
                                            const int* __restrict__ part,
                                            int* __restrict__ cscan) {
    __shared__ int sh[1024];
    int t = threadIdx.x;
    int i = blockIdx.x * 1024 + t;
    int v = (i < M_CNT) ? cnt[i] : 0;
    sh[t] = v;
    __syncthreads();
    for (int o = 1; o < 1024; o <<= 1) {
        int u = (t >= o) ? sh[t - o] : 0;
        __syncthreads();
        sh[t] += u;
        __syncthreads();
    }
    if (i < M_CNT) cscan[i] = part[blockIdx.x] + sh[t] - v;
}

// A3: scatter (dst,src) pairs into bucket runs (contiguous per (tile,bucket))
__global__ __launch_bounds__(256) void kA3(const int* __restrict__ src,
                                           const int* __restrict__ dst,
                                           const int* __restrict__ cscan,
                                           int2* __restrict__ pairs) {
    __shared__ int hoff[NBKT];
    int t = threadIdx.x;
    for (int i = t; i < NBKT; i += 256) hoff[i] = cscan[i * NT + blockIdx.x];
    __syncthreads();
    int base = blockIdx.x * EPB;
#pragma unroll
    for (int r = 0; r < EPB / 256; ++r) {
        int e = base + r * 256 + t;
        if (e < NE) {
            int d = dst[e], s = src[e];
            int pos = atomicAdd(&hoff[d >> 7], 1);
            pairs[pos] = make_int2(d, s);
        }
    }
}

// B2: per-bucket LDS counting sort -> csrc stream + offs/dinv/dn2 (no global atomics)
__global__ __launch_bounds__(256) void kB2(const int2* __restrict__ pairs,
                                           const int* __restrict__ cscan,
                                           int* __restrict__ csrc,
                                           int* __restrict__ offs,
                                           float* __restrict__ dinv,
                                           float* __restrict__ dn2) {
    __shared__ int ld[CAP], ls[CAP], lo[CAP];
    __shared__ int hist[NPB], pre[NPB], curl[NPB];
    int b = blockIdx.x, t = threadIdx.x;
    int s = cscan[b * NT];
    int e = (b == NBKT - 1) ? NE : cscan[(b + 1) * NT];
    int cnt = min(e - s, CAP);
    int nbase = b * NPB;
    if (t < NPB) hist[t] = 0;
    __syncthreads();
    for (int i = t; i < cnt; i += 256) {
        int2 p = pairs[s + i];
        int dl = p.x - nbase;
        ld[i] = dl; ls[i] = p.y;
        atomicAdd(&hist[dl], 1);
    }
    __syncthreads();
    int dg = (t < NPB) ? hist[t] : 0;
    if (t < NPB) pre[t] = dg;
    __syncthreads();
    for (int o = 1; o < NPB; o <<= 1) {
        int u = (t < NPB && t >= o) ? pre[t - o] : 0;
        __syncthreads();
        if (t < NPB) pre[t] += u;
        __syncthreads();
    }
    if (t < NPB) {
        int ex = pre[t] - dg;          // exclusive local prefix
        curl[t] = ex;
        int n = nbase + t;
        if (n < NN) {
            offs[n] = s + ex;
            float r = rsqrtf((float)(dg + 1));   // deg = in-edges + self loop
            dinv[n] = r;
            dn2[n] = r * r;
        }
    }
    if (b == 0 && t == 0) offs[NN] = NE;
    __syncthreads();
    for (int i = t; i < cnt; i += 256) {
        int pos = atomicAdd(&curl[ld[i]], 1);    // LDS atomic only
        lo[pos] = ls[i];
    }
    __syncthreads();
    for (int i = t; i < cnt; i += 256) csrc[s + i] = lo[i];   // full-line stream
}

// u0 = dinv (.) x   (fp32 -> fp16, 2 elems/thread)
__global__ void k_u0(const float2* __restrict__ x2, const float* __restrict__ dinv,
                     __half2* __restrict__ u2) {
    int i = blockIdx.x * blockDim.x + threadIdx.x;   // NN*F/2
    if (i >= NN * F / 2) return;
    float2 v = x2[i];
    float d = dinv[i >> 5];
    u2[i] = __floats2half2_rn(v.x * d, v.y * d);
}

// u_out[n,:] = oscale[n] * (u_in[n,:] + sum_{s in Nin(n)} u_in[s,:])
// wave = 2 nodes: lanes 0-31 -> node 2w, lanes 32-63 -> node 2w+1
__global__ __launch_bounds__(256) void k_hop(const int* __restrict__ offs,
                                             const int* __restrict__ csrc,
                                             const float* __restrict__ oscale,
                                             const __half2* __restrict__ uin,
                                             __half2* __restrict__ uout) {
    int wv = blockIdx.x * 4 + (threadIdx.x >> 6);
    int lane = threadIdx.x & 63;
    int n = wv * 2 + (lane >> 5);      // NN = 12500*4*2 exactly
    int c = lane & 31;
    float2 acc = __half22float2(uin[n * 32 + c]);
    int e = offs[n], end = offs[n + 1];
    for (; e + 8 <= end; e += 8) {
        int s0 = csrc[e],     s1 = csrc[e + 1], s2 = csrc[e + 2], s3 = csrc[e + 3];
        int s4 = csrc[e + 4], s5 = csrc[e + 5], s6 = csrc[e + 6], s7 = csrc[e + 7];
        float2 f0 = __half22float2(uin[s0 * 32 + c]);
        float2 f1 = __half22float2(uin[s1 * 32 + c]);
        float2 f2 = __half22float2(uin[s2 * 32 + c]);
        float2 f3 = __half22float2(uin[s3 * 32 + c]);
        float2 f4 = __half22float2(uin[s4 * 32 + c]);
        float2 f5 = __half22float2(uin[s5 * 32 + c]);
        float2 f6 = __half22float2(uin[s6 * 32 + c]);
        float2 f7 = __half22float2(uin[s7 * 32 + c]);
        acc.x += ((f0.x + f1.x) + (f2.x + f3.x)) + ((f4.x + f5.x) + (f6.x + f7.x));
        acc.y += ((f0.y + f1.y) + (f2.y + f3.y)) + ((f4.y + f5.y) + (f6.y + f7.y));
    }
    for (; e < end; ++e) {
        float2 f = __half22float2(uin[csrc[e] * 32 + c]);
        acc.x += f.x; acc.y += f.y;
    }
    float os = oscale[n];
    uout[n * 32 + c] = __floats2half2_rn(acc.x * os, acc.y * os);
}

// y = relu(h @ Wh^T + b) via MFMA; per-block partial stats -> psum (NO atomics)
__global__ __launch_bounds__(256) void k_linear(const __half* __restrict__ h,
                                                const __half* __restrict__ Wh,
                                                const float* __restrict__ bg,
                                                __half* __restrict__ y,
                                                float* __restrict__ psum) {
    __shared__ float sred[4][64], qred[4][64];
    int tid = threadIdx.x;
    int wid = tid >> 6, lane = tid & 63;
    int lo = lane & 15, hi = lane >> 4;
    int n0 = blockIdx.x * 64 + wid * 16;

    half8 bf[4][2];
#pragma unroll
    for (int ct = 0; ct < 4; ++ct)
#pragma unroll
        for (int kk = 0; kk < 2; ++kk)
            bf[ct][kk] = *(const half8*)(Wh + (ct * 16 + lo) * 64 + kk * 32 + hi * 8);

    int arow = n0 + lo;
    half8 af[2];
    if (arow < NN) {
        af[0] = *(const half8*)(h + arow * 64 + hi * 8);
        af[1] = *(const half8*)(h + arow * 64 + 32 + hi * 8);
    } else {
#pragma unroll
        for (int j = 0; j < 8; ++j) { af[0][j] = (_Float16)0; af[1][j] = (_Float16)0; }
    }

    f32x4 acc[4];
#pragma unroll
    for (int ct = 0; ct < 4; ++ct) {
        acc[ct] = (f32x4){0.f, 0.f, 0.f, 0.f};
        acc[ct] = __builtin_amdgcn_mfma_f32_16x16x32_f16(af[0], bf[ct][0], acc[ct], 0, 0, 0);
        acc[ct] = __builtin_amdgcn_mfma_f32_16x16x32_f16(af[1], bf[ct][1], acc[ct], 0, 0, 0);
    }

#pragma unroll
    for (int ct = 0; ct < 4; ++ct) {
        int j = ct * 16 + lo;
        float bj = bg[j];
        float ls = 0.f, lq = 0.f;
#pragma unroll
        for (int r = 0; r < 4; ++r) {
            int n = n0 + hi * 4 + r;
            if (n < NN) {
                float v = fmaxf(acc[ct][r] + bj, 0.f);
                y[n * 64 + j] = __float2half(v);
                ls += v; lq += v * v;
            }
        }
        ls += __shfl_xor(ls, 16, 64); ls += __shfl_xor(ls, 32, 64);
        lq += __shfl_xor(lq, 16, 64); lq += __shfl_xor(lq, 32, 64);
        if (hi == 0) { sred[wid][j] = ls; qred[wid][j] = lq; }
    }
    __syncthreads();
    if (tid < 128) {
        int c = tid & 63;
        float v = (tid < 64)
            ? (sred[0][c] + sred[1][c] + sred[2][c] + sred[3][c])
            : (qred[0][c] + qred[1][c] + qred[2][c] + qred[3][c]);
        psum[blockIdx.x * 128 + tid] = v;    // streaming full-line write
    }
}

// reduce psum[NLB][128] -> sums[128]; only 16*128 spread-out atomics
__global__ __launch_bounds__(256) void k_red(const float* __restrict__ psum,
                                             float* __restrict__ sums) {
    int t = threadIdx.x;
    int c = t & 127, half = t >> 7;           // 2 threads per column
    int r0 = blockIdx.x * RPB + half;
    int r1 = min((int)(blockIdx.x + 1) * RPB, NLB);
    float s = 0.f;
    for (int r = r0; r < r1; r += 2)
        s += psum[r * 128 + c];
    __shared__ float sh[128];
    if (half == 0) sh[c] = s;
    __syncthreads();
    if (half == 1) {
        float v = s + sh[c];
        fatomic_add(&sums[c], v);
    }
}

// BN affine (recomputed per block from sums) + normalize + pooled segment-sum
__global__ __launch_bounds__(256) void k_normpool(const __half* __restrict__ y,
                                                  const int* __restrict__ batch,
                                                  const float* __restrict__ sums,
                                                  const float* __restrict__ gamma,
                                                  const float* __restrict__ beta,
                                                  float* __restrict__ outh,
                                                  float* __restrict__ pooled) {
    int tid = threadIdx.x;
    int j = tid & 63, nl = tid >> 6;
    float mean = sums[j] * (1.0f / NN);
    float var = sums[64 + j] * (1.0f / NN) - mean * mean;
    float rinv = rsqrtf(var + BN_EPS);
    float a = gamma[j] * rinv;
    float c = beta[j] - mean * a;
    int base = blockIdx.x * 256;
    int curg = -1;
    float acc = 0.f;
    for (int it = 0; it < 64; ++it) {
        int n = base + it * 4 + nl;
        if (n >= NN) break;
        int g = batch[n];
        float v = fmaf(__half2float(y[n * 64 + j]), a, c);
        outh[(size_t)n * 64 + j] = v;
        if (g != curg) {
            if (curg >= 0) fatomic_add(&pooled[curg * 64 + j], acc);
            curg = g; acc = 0.f;
        }
        acc += v;
    }
    if (curg >= 0) fatomic_add(&pooled[curg * 64 + j], acc);
}

extern "C" void kernel_launch(void* const* d_in, const int* in_sizes, int n_in,
                              void* d_out, int out_size, void* d_ws, size_t ws_size,
                              hipStream_t stream) {
    const float* x     = (const float*)d_in[0];
    const int*   ei    = (const int*)d_in[1];
    const int*   batch = (const int*)d_in[2];
    const float* W     = (const float*)d_in[3];
    const float* b     = (const float*)d_in[4];
    const float* gamma = (const float*)d_in[5];
    const float* beta  = (const float*)d_in[6];
    const int* src = ei;
    const int* dst = ei + NE;

    float* pooled = (float*)d_out;
    float* outh   = (float*)d_out + NG * F;

    char* w = (char*)d_ws;
    float* dinv  = (float*)w;  w += sizeof(float) * NN;
    float* dn2   = (float*)w;  w += sizeof(float) * NN;
    int*   offs  = (int*)w;    w += sizeof(int) * (NN + 1);
    float* sums  = (float*)w;  w += sizeof(float) * 2 * F;
    __half* Wh   = (__half*)w; w += sizeof(__half) * F * F;
    float* psum  = (float*)w;  w += sizeof(float) * NLB * 128;
    int*   cnt   = (int*)w;    w += sizeof(int) * M_CNT;
    int*   cscan = (int*)w;    w += sizeof(int) * M_CNT;
    int*   part  = (int*)w;    w += sizeof(int) * 256;
    int*   csrc  = (int*)w;    w += sizeof(int) * NE;
    // union region (25.6 MB): pairs (12.8 MB, live A3..B2) -> ubufA (u0 onward)
    char* uni = w;
    __half* ubufA = (__half*)uni;
    __half* ubufB = (__half*)(uni + sizeof(__half) * NN * F);
    int2*   pairs = (int2*)uni;

    const int B = 256;
    dim3 blk(B);

    kA1<<<dim3(NT), blk, 0, stream>>>(dst, cnt, pooled, sums, W, Wh);
    kS1<<<dim3(NSB), dim3(1024), 0, stream>>>(cnt, part);
    kS2<<<dim3(1), blk, 0, stream>>>(part);
    kS3<<<dim3(NSB), dim3(1024), 0, stream>>>(cnt, part, cscan);
    kA3<<<dim3(NT), blk, 0, stream>>>(src, dst, cscan, pairs);
    kB2<<<dim3(NBKT), blk, 0, stream>>>(pairs, cscan, csrc, offs, dinv, dn2);

    // u0 = dinv.x -> ubufA  (pairs dead from here on)
    k_u0<<<dim3((NN * F / 2 + B - 1) / B), blk, 0, stream>>>((const float2*)x, dinv, (__half2*)ubufA);

    dim3 gh(NN / 8);   // 12500 blocks, 4 waves/block, 2 nodes/wave
    k_hop<<<gh, blk, 0, stream>>>(offs, csrc, dn2,  (const __half2*)ubufA, (__half2*)ubufB);
    k_hop<<<gh, blk, 0, stream>>>(offs, csrc, dn2,  (const __half2*)ubufB, (__half2*)ubufA);
    k_hop<<<gh, blk, 0, stream>>>(offs, csrc, dinv, (const __half2*)ubufA, (__half2*)ubufB);

    // linear + relu (MFMA) with contention-free stats: ubufB(h) -> y in ubufA
    __half* yh = ubufA;
    k_linear<<<dim3(NLB), blk, 0, stream>>>(ubufB, Wh, b, yh, psum);
    k_red<<<dim3(RED_B), blk, 0, stream>>>(psum, sums);
    k_normpool<<<dim3((NN + 255) / 256), blk, 0, stream>>>(yh, batch, sums, gamma, beta, outh, pooled);
}